// Round 6
// baseline (372.244 us; speedup 1.0000x reference)
//
#include <hip/hip_runtime.h>

typedef __attribute__((ext_vector_type(8))) short short8_t;
typedef __attribute__((ext_vector_type(4))) short short4_t;
typedef __attribute__((ext_vector_type(4))) float float4_t;

#define MFMA16(a, b, c) __builtin_amdgcn_mfma_f32_16x16x32_bf16((a), (b), (c), 0, 0, 0)

// fp32 -> bf16 round-to-nearest-even (finite inputs only)
static __device__ __forceinline__ unsigned short f2b(float f) {
  unsigned int x = __builtin_bit_cast(unsigned int, f);
  x = (x + 0x7fffu + ((x >> 16) & 1u)) >> 16;
  return (unsigned short)x;
}

// ---------------------------------------------------------------------------
// Kernel 1: MT[j][d] = (1/32) * sum_k binding[j][k] * Wq[d][k]   (bf16 out)
// ---------------------------------------------------------------------------
__global__ __launch_bounds__(256, 2) void mt_kernel(
    const float* __restrict__ Wq, const float* __restrict__ binding,
    short* __restrict__ MT) {
  __shared__ short bl[64 * 64];
  __shared__ short wl[128 * 64];
  const int tid = threadIdx.x;
  const int wid = tid >> 6;
  const int lane = tid & 63;
  const int ml = lane & 15;
  const int g = lane >> 4;
  const int klane = g * 8;
  const int j0 = blockIdx.x * 64;
  const int d0 = blockIdx.y * 128;

  float4_t acc[4][2];
#pragma unroll
  for (int a = 0; a < 4; ++a)
#pragma unroll
    for (int b = 0; b < 2; ++b) acc[a][b] = (float4_t)(0.0f);

  const int sr = tid >> 3;
  const int sc = (tid & 7) << 3;

  for (int kc = 0; kc < 1024; kc += 64) {
#pragma unroll
    for (int rr = sr; rr < 64; rr += 32) {
      const float* s = binding + (size_t)(j0 + rr) * 1024 + kc + sc;
      float4 f0 = *(const float4*)s;
      float4 f1 = *(const float4*)(s + 4);
      short8_t v;
      v[0] = (short)f2b(f0.x); v[1] = (short)f2b(f0.y);
      v[2] = (short)f2b(f0.z); v[3] = (short)f2b(f0.w);
      v[4] = (short)f2b(f1.x); v[5] = (short)f2b(f1.y);
      v[6] = (short)f2b(f1.z); v[7] = (short)f2b(f1.w);
      *(short8_t*)((char*)bl + ((((rr * 64 + sc) * 2) ^ ((rr & 7) << 4)))) = v;
    }
#pragma unroll
    for (int rr = sr; rr < 128; rr += 32) {
      const float* s = Wq + (size_t)(d0 + rr) * 1024 + kc + sc;
      float4 f0 = *(const float4*)s;
      float4 f1 = *(const float4*)(s + 4);
      short8_t v;
      v[0] = (short)f2b(f0.x); v[1] = (short)f2b(f0.y);
      v[2] = (short)f2b(f0.z); v[3] = (short)f2b(f0.w);
      v[4] = (short)f2b(f1.x); v[5] = (short)f2b(f1.y);
      v[6] = (short)f2b(f1.z); v[7] = (short)f2b(f1.w);
      *(short8_t*)((char*)wl + ((((rr * 64 + sc) * 2) ^ ((rr & 7) << 4)))) = v;
    }
    __syncthreads();
#pragma unroll
    for (int ks = 0; ks < 2; ++ks) {
      const int col = ks * 32 + klane;
      short8_t af[4], bfr[2];
#pragma unroll
      for (int mr = 0; mr < 4; ++mr) {
        int row = mr * 16 + ml;
        af[mr] = *(const short8_t*)((const char*)bl +
                                    (((row * 64 + col) * 2) ^ ((row & 7) << 4)));
      }
#pragma unroll
      for (int nr = 0; nr < 2; ++nr) {
        int row = wid * 32 + nr * 16 + ml;
        bfr[nr] = *(const short8_t*)((const char*)wl +
                                     (((row * 64 + col) * 2) ^ ((row & 7) << 4)));
      }
#pragma unroll
      for (int mr = 0; mr < 4; ++mr)
#pragma unroll
        for (int nr = 0; nr < 2; ++nr)
          acc[mr][nr] = MFMA16(af[mr], bfr[nr], acc[mr][nr]);
    }
    __syncthreads();
  }
#pragma unroll
  for (int mr = 0; mr < 4; ++mr)
#pragma unroll
    for (int nr = 0; nr < 2; ++nr)
#pragma unroll
      for (int i = 0; i < 4; ++i) {
        int j = j0 + mr * 16 + g * 4 + i;
        int d = d0 + wid * 32 + nr * 16 + ml;
        MT[(size_t)j * 1024 + d] = (short)f2b(acc[mr][nr][i] * 0.03125f);
      }
}

// ---------------------------------------------------------------------------
// Kernel 2: symT[k][j] = bf16(symbols[j][k])  (transpose 512x1024 -> 1024x512)
// ---------------------------------------------------------------------------
__global__ __launch_bounds__(256) void tr_kernel(const float* __restrict__ sym,
                                                 short* __restrict__ symT) {
  __shared__ short t[64][65];
  const int tid = threadIdx.x;
  const int k0 = blockIdx.x * 64;
  const int j0 = blockIdx.y * 64;
  const int sr = tid >> 3;
  const int sc = (tid & 7) << 3;
#pragma unroll
  for (int rr = sr; rr < 64; rr += 32) {
    const float* s = sym + (size_t)(j0 + rr) * 1024 + k0 + sc;
    float4 f0 = *(const float4*)s;
    float4 f1 = *(const float4*)(s + 4);
    t[rr][sc + 0] = (short)f2b(f0.x); t[rr][sc + 1] = (short)f2b(f0.y);
    t[rr][sc + 2] = (short)f2b(f0.z); t[rr][sc + 3] = (short)f2b(f0.w);
    t[rr][sc + 4] = (short)f2b(f1.x); t[rr][sc + 5] = (short)f2b(f1.y);
    t[rr][sc + 6] = (short)f2b(f1.z); t[rr][sc + 7] = (short)f2b(f1.w);
  }
  __syncthreads();
  const int kk = tid >> 4;
  const int jj = (tid & 15) << 2;
#pragma unroll
  for (int k = kk; k < 64; k += 16) {
    short* dst = symT + (size_t)(k0 + k) * 512 + j0 + jj;
    dst[0] = t[jj + 0][k];
    dst[1] = t[jj + 1][k];
    dst[2] = t[jj + 2][k];
    dst[3] = t[jj + 3][k];
  }
}

// ---------------------------------------------------------------------------
// Kernel 3: score. logitsT = MT @ bf16(inp)^T (swapped operands), row max,
// P = bf16(exp(x - m)) UNNORMALIZED -> global ws, rowinv = 1/rowsum (fp32).
// grid 512 (64-row tiles), block 512 (8 waves), wave owns a 64-j strip.
// BK=128 per barrier: stage TWO 64-col tiles into a ping-pong buffer PAIR,
// one barrier covers 64 MFMA/wave. Ordering: reads(s) vs writes(s+2,same
// pair) are separated by barrier(s+1) + per-wave lgkm drain (R5-proven).
// sched_barrier(0) after the raw barrier = the R2/R3 race fix (rule #18).
// ---------------------------------------------------------------------------
__global__ __launch_bounds__(512, 4) void score_kernel(
    const float* __restrict__ inp, const short* __restrict__ MT,
    short* __restrict__ P, float* __restrict__ rowinv) {
  __shared__ short Abuf[4][64 * 64];
  __shared__ float redmax[8 * 64];
  __shared__ float redsum[8 * 64];

  const int tid = threadIdx.x;
  const int wid = tid >> 6;
  const int lane = tid & 63;
  const int ml = lane & 15;
  const int g = lane >> 4;
  const size_t row0 = (size_t)blockIdx.x * 64;

  float4_t acc[4][4];  // acc[jm][rm]: D[j][r], j = wid*64+jm*16+g*4+i, r = rm*16+ml
#pragma unroll
  for (int a = 0; a < 4; ++a)
#pragma unroll
    for (int b = 0; b < 4; ++b) acc[a][b] = (float4_t)(0.0f);

  const int sr = tid >> 3;        // 0..63 row within tile
  const int sc = (tid & 7) << 3;  // col chunk
  const float* srcbase = inp + (row0 + sr) * 1024 + sc;
  const short* mtbase = MT + (size_t)(wid * 64 + ml) * 1024 + g * 8;
  const int lds_off = ((sr * 64 + sc) * 2) ^ ((sr & 7) << 4);

  // prefetch tiles 0 and 1 (fp32)
  float4 f0 = *(const float4*)(srcbase);
  float4 f1 = *(const float4*)(srcbase + 4);
  float4 f2 = *(const float4*)(srcbase + 64);
  float4 f3 = *(const float4*)(srcbase + 68);

  for (int s = 0; s < 8; ++s) {
    const int b0 = (s & 1) << 1;  // buffer pair {b0, b0+1}
    // convert + stage tile 2s -> Abuf[b0], tile 2s+1 -> Abuf[b0+1]
    short8_t v;
    v[0] = (short)f2b(f0.x); v[1] = (short)f2b(f0.y);
    v[2] = (short)f2b(f0.z); v[3] = (short)f2b(f0.w);
    v[4] = (short)f2b(f1.x); v[5] = (short)f2b(f1.y);
    v[6] = (short)f2b(f1.z); v[7] = (short)f2b(f1.w);
    *(short8_t*)((char*)Abuf[b0] + lds_off) = v;
    v[0] = (short)f2b(f2.x); v[1] = (short)f2b(f2.y);
    v[2] = (short)f2b(f2.z); v[3] = (short)f2b(f2.w);
    v[4] = (short)f2b(f3.x); v[5] = (short)f2b(f3.y);
    v[6] = (short)f2b(f3.z); v[7] = (short)f2b(f3.w);
    *(short8_t*)((char*)Abuf[b0 + 1] + lds_off) = v;

    // MT fragments for tile 2s — global, issued before the barrier so L2
    // latency hides under barrier + ds_reads
    const short* mtb0 = mtbase + s * 128;
    short8_t af0[4], af1[4];
#pragma unroll
    for (int jm = 0; jm < 4; ++jm) {
      af0[jm] = *(const short8_t*)(mtb0 + jm * 16 * 1024);
      af1[jm] = *(const short8_t*)(mtb0 + jm * 16 * 1024 + 32);
    }

    // prefetch tiles 2s+2, 2s+3 (consumed next super-iteration)
    if (s < 7) {
      const float* s2 = srcbase + (s + 1) * 128;
      f0 = *(const float4*)s2;
      f1 = *(const float4*)(s2 + 4);
      f2 = *(const float4*)(s2 + 64);
      f3 = *(const float4*)(s2 + 68);
    }

    // drain own LDS writes; global loads stay in flight
    asm volatile("s_waitcnt lgkmcnt(0)" ::: "memory");
    __builtin_amdgcn_s_barrier();
    __builtin_amdgcn_sched_barrier(0);

    // ---- tile 2s: ds_reads from Abuf[b0] + 32 MFMA ----
    const char* bb0 = (const char*)Abuf[b0];
#pragma unroll
    for (int ks = 0; ks < 2; ++ks) {
      const int col = ks * 32 + g * 8;
      short8_t bfr[4];
#pragma unroll
      for (int rm = 0; rm < 4; ++rm) {
        int row = rm * 16 + ml;
        bfr[rm] = *(const short8_t*)(bb0 + (((row * 64 + col) * 2) ^ ((row & 7) << 4)));
      }
#pragma unroll
      for (int jm = 0; jm < 4; ++jm)
#pragma unroll
        for (int rm = 0; rm < 4; ++rm)
          acc[jm][rm] = MFMA16(ks == 0 ? af0[jm] : af1[jm], bfr[rm], acc[jm][rm]);
    }

    // MT fragments for tile 2s+1 (overlap with tile-2s MFMAs above)
    const short* mtb1 = mtbase + s * 128 + 64;
    short8_t ag0[4], ag1[4];
#pragma unroll
    for (int jm = 0; jm < 4; ++jm) {
      ag0[jm] = *(const short8_t*)(mtb1 + jm * 16 * 1024);
      ag1[jm] = *(const short8_t*)(mtb1 + jm * 16 * 1024 + 32);
    }

    // ---- tile 2s+1: ds_reads from Abuf[b0+1] + 32 MFMA ----
    const char* bb1 = (const char*)Abuf[b0 + 1];
#pragma unroll
    for (int ks = 0; ks < 2; ++ks) {
      const int col = ks * 32 + g * 8;
      short8_t bfr[4];
#pragma unroll
      for (int rm = 0; rm < 4; ++rm) {
        int row = rm * 16 + ml;
        bfr[rm] = *(const short8_t*)(bb1 + (((row * 64 + col) * 2) ^ ((row & 7) << 4)));
      }
#pragma unroll
      for (int jm = 0; jm < 4; ++jm)
#pragma unroll
        for (int rm = 0; rm < 4; ++rm)
          acc[jm][rm] = MFMA16(ks == 0 ? ag0[jm] : ag1[jm], bfr[rm], acc[jm][rm]);
    }
  }

  // ---- row max over j (512), rows r = rm*16+ml ----
#pragma unroll
  for (int rm = 0; rm < 4; ++rm) {
    float mx = -1e30f;
#pragma unroll
    for (int jm = 0; jm < 4; ++jm)
#pragma unroll
      for (int i = 0; i < 4; ++i) mx = fmaxf(mx, acc[jm][rm][i]);
    mx = fmaxf(mx, __shfl_xor(mx, 16));
    mx = fmaxf(mx, __shfl_xor(mx, 32));
    if (g == 0) redmax[wid * 64 + rm * 16 + ml] = mx;
  }
  __syncthreads();

  // ---- exp(x-m), write unnormalized bf16 P, reduce row sums ----
#pragma unroll
  for (int rm = 0; rm < 4; ++rm) {
    const int row = rm * 16 + ml;
    float m = redmax[row];
#pragma unroll
    for (int w = 1; w < 8; ++w) m = fmaxf(m, redmax[w * 64 + row]);
    float s = 0.0f;
#pragma unroll
    for (int jm = 0; jm < 4; ++jm) {
      short4_t pv;
#pragma unroll
      for (int i = 0; i < 4; ++i) {
        float p = __expf(acc[jm][rm][i] - m);
        s += p;
        pv[i] = (short)f2b(p);
      }
      *(short4_t*)(P + ((row0 + row) << 9) + wid * 64 + jm * 16 + g * 4) = pv;
    }
    s += __shfl_xor(s, 16);
    s += __shfl_xor(s, 32);
    if (g == 0) redsum[wid * 64 + row] = s;
  }
  __syncthreads();

  // ---- wave 0 writes 1/rowsum ----
  if (wid == 0 && g == 0) {
#pragma unroll
    for (int rm = 0; rm < 4; ++rm) {
      const int row = rm * 16 + ml;
      float t = 0.0f;
#pragma unroll
      for (int w = 0; w < 8; ++w) t += redsum[w * 64 + row];
      rowinv[row0 + row] = 1.0f / t;
    }
  }
}

// ---------------------------------------------------------------------------
// Kernel 4: out[r][d] = rowinv[r] * sum_j P[r][j] * symT[d][j].  128x128 tile,
// 256 threads (4 waves, 2x2). NO LDS, NO barriers: both operands are bf16 and
// L2-resident (P panel = 4MB/XCD under the swizzle; symT = 1MB); MFMA A/B
// fragments load directly from global as b128 (lane&15 -> row, lane>>4 ->
// k-chunk; rows are 1KB-strided so each 16-lane group reads full 64B lines).
// Pure load->MFMA dataflow, compiler-pipelined, latency hidden by 12 waves/CU.
// XCD-bijective block swizzle keeps each XCD's P panel in its private L2.
// ---------------------------------------------------------------------------
__global__ __launch_bounds__(256, 3) void pv_kernel(
    const short* __restrict__ P, const short* __restrict__ symT,
    const float* __restrict__ rowinv, float* __restrict__ out) {
  const int tid = threadIdx.x;
  const int lane = tid & 63;
  const int ml = lane & 15;
  const int g = lane >> 4;
  const int wid = tid >> 6;
  const int wr = wid >> 1;
  const int wc = wid & 1;

  const int b = blockIdx.x;
  const int swz = (b & 7) * 256 + (b >> 3);
  const size_t m0 = (size_t)(swz >> 3) * 128;
  const int n0 = (swz & 7) * 128;

  float4_t acc[4][4];
#pragma unroll
  for (int a = 0; a < 4; ++a)
#pragma unroll
    for (int c = 0; c < 4; ++c) acc[a][c] = (float4_t)(0.0f);

  // lane-fixed fragment bases: row = base + frag*16 + ml, k-chunk = g*8
  const short* abase = P + (m0 + wr * 64 + ml) * 512 + g * 8;
  const short* bbase = symT + (size_t)(n0 + wc * 64 + ml) * 512 + g * 8;

#pragma unroll
  for (int k8 = 0; k8 < 16; ++k8) {  // 16 steps of K=32
    const int off = k8 * 32;
    short8_t af[4], bf[4];
#pragma unroll
    for (int mr = 0; mr < 4; ++mr)
      af[mr] = *(const short8_t*)(abase + mr * 16 * 512 + off);
#pragma unroll
    for (int nr = 0; nr < 4; ++nr)
      bf[nr] = *(const short8_t*)(bbase + nr * 16 * 512 + off);
#pragma unroll
    for (int mr = 0; mr < 4; ++mr)
#pragma unroll
      for (int nr = 0; nr < 4; ++nr)
        acc[mr][nr] = MFMA16(af[mr], bf[nr], acc[mr][nr]);
  }

#pragma unroll
  for (int mr = 0; mr < 4; ++mr)
#pragma unroll
    for (int i = 0; i < 4; ++i) {
      const size_t r = m0 + wr * 64 + mr * 16 + g * 4 + i;
      const float inv = rowinv[r];
#pragma unroll
      for (int nr = 0; nr < 4; ++nr)
        out[r * 1024 + n0 + wc * 64 + nr * 16 + ml] = acc[mr][nr][i] * inv;
    }
}

extern "C" void kernel_launch(void* const* d_in, const int* in_sizes, int n_in,
                              void* d_out, int out_size, void* d_ws,
                              size_t ws_size, hipStream_t stream) {
  const float* inp = (const float*)d_in[0];      // [8,4096,1024]
  const float* Wq = (const float*)d_in[1];       // [1024,1024]
  const float* binding = (const float*)d_in[2];  // [512,1024]
  const float* symbols = (const float*)d_in[3];  // [512,1024]
  float* out = (float*)d_out;                    // [8,4096,1024]

  short* MT = (short*)d_ws;            // [512][1024] bf16 (1/32 scale folded)
  short* symT = MT + 512 * 1024;       // [1024][512] bf16
  short* P = symT + 1024 * 512;        // [32768][512] bf16 unnormalized exp
  float* rowinv = (float*)(P + (size_t)32768 * 512);  // [32768] fp32

  mt_kernel<<<dim3(8, 8), 256, 0, stream>>>(Wq, binding, MT);
  tr_kernel<<<dim3(16, 8), 256, 0, stream>>>(symbols, symT);
  score_kernel<<<512, 512, 0, stream>>>(inp, MT, P, rowinv);
  pv_kernel<<<2048, 256, 0, stream>>>(P, symT, rowinv, out);
}

// Round 7
// 213.988 us; speedup vs baseline: 1.7396x; 1.7396x over previous
//
#include <hip/hip_runtime.h>

typedef __attribute__((ext_vector_type(8))) short short8_t;
typedef __attribute__((ext_vector_type(4))) short short4_t;
typedef __attribute__((ext_vector_type(4))) float float4_t;

#define MFMA16(a, b, c) __builtin_amdgcn_mfma_f32_16x16x32_bf16((a), (b), (c), 0, 0, 0)
#define GLOAD_LDS16(g, l)                                                   \
  __builtin_amdgcn_global_load_lds(                                         \
      (const __attribute__((address_space(1))) void*)(g),                   \
      (__attribute__((address_space(3))) void*)(l), 16, 0, 0)

// fp32 -> bf16 round-to-nearest-even (finite inputs only)
static __device__ __forceinline__ unsigned short f2b(float f) {
  unsigned int x = __builtin_bit_cast(unsigned int, f);
  x = (x + 0x7fffu + ((x >> 16) & 1u)) >> 16;
  return (unsigned short)x;
}

static __device__ __forceinline__ short8_t pack8(float4 x, float4 y) {
  short8_t v;
  v[0] = (short)f2b(x.x); v[1] = (short)f2b(x.y);
  v[2] = (short)f2b(x.z); v[3] = (short)f2b(x.w);
  v[4] = (short)f2b(y.x); v[5] = (short)f2b(y.y);
  v[6] = (short)f2b(y.z); v[7] = (short)f2b(y.w);
  return v;
}

// ---------------------------------------------------------------------------
// Kernel 1: MT[j][d] = (1/32) * sum_k binding[j][k] * Wq[d][k]   (bf16 out)
// ---------------------------------------------------------------------------
__global__ __launch_bounds__(256, 2) void mt_kernel(
    const float* __restrict__ Wq, const float* __restrict__ binding,
    short* __restrict__ MT) {
  __shared__ short bl[64 * 64];
  __shared__ short wl[128 * 64];
  const int tid = threadIdx.x;
  const int wid = tid >> 6;
  const int lane = tid & 63;
  const int ml = lane & 15;
  const int g = lane >> 4;
  const int klane = g * 8;
  const int j0 = blockIdx.x * 64;
  const int d0 = blockIdx.y * 128;

  float4_t acc[4][2];
#pragma unroll
  for (int a = 0; a < 4; ++a)
#pragma unroll
    for (int b = 0; b < 2; ++b) acc[a][b] = (float4_t)(0.0f);

  const int sr = tid >> 3;
  const int sc = (tid & 7) << 3;

  for (int kc = 0; kc < 1024; kc += 64) {
#pragma unroll
    for (int rr = sr; rr < 64; rr += 32) {
      const float* s = binding + (size_t)(j0 + rr) * 1024 + kc + sc;
      float4 f0 = *(const float4*)s;
      float4 f1 = *(const float4*)(s + 4);
      *(short8_t*)((char*)bl + ((((rr * 64 + sc) * 2) ^ ((rr & 7) << 4)))) =
          pack8(f0, f1);
    }
#pragma unroll
    for (int rr = sr; rr < 128; rr += 32) {
      const float* s = Wq + (size_t)(d0 + rr) * 1024 + kc + sc;
      float4 f0 = *(const float4*)s;
      float4 f1 = *(const float4*)(s + 4);
      *(short8_t*)((char*)wl + ((((rr * 64 + sc) * 2) ^ ((rr & 7) << 4)))) =
          pack8(f0, f1);
    }
    __syncthreads();
#pragma unroll
    for (int ks = 0; ks < 2; ++ks) {
      const int col = ks * 32 + klane;
      short8_t af[4], bfr[2];
#pragma unroll
      for (int mr = 0; mr < 4; ++mr) {
        int row = mr * 16 + ml;
        af[mr] = *(const short8_t*)((const char*)bl +
                                    (((row * 64 + col) * 2) ^ ((row & 7) << 4)));
      }
#pragma unroll
      for (int nr = 0; nr < 2; ++nr) {
        int row = wid * 32 + nr * 16 + ml;
        bfr[nr] = *(const short8_t*)((const char*)wl +
                                     (((row * 64 + col) * 2) ^ ((row & 7) << 4)));
      }
#pragma unroll
      for (int mr = 0; mr < 4; ++mr)
#pragma unroll
        for (int nr = 0; nr < 2; ++nr)
          acc[mr][nr] = MFMA16(af[mr], bfr[nr], acc[mr][nr]);
    }
    __syncthreads();
  }
#pragma unroll
  for (int mr = 0; mr < 4; ++mr)
#pragma unroll
    for (int nr = 0; nr < 2; ++nr)
#pragma unroll
      for (int i = 0; i < 4; ++i) {
        int j = j0 + mr * 16 + g * 4 + i;
        int d = d0 + wid * 32 + nr * 16 + ml;
        MT[(size_t)j * 1024 + d] = (short)f2b(acc[mr][nr][i] * 0.03125f);
      }
}

// ---------------------------------------------------------------------------
// Kernel 2: symT[k][j] = bf16(symbols[j][k])  (transpose 512x1024 -> 1024x512)
// ---------------------------------------------------------------------------
__global__ __launch_bounds__(256) void tr_kernel(const float* __restrict__ sym,
                                                 short* __restrict__ symT) {
  __shared__ short t[64][65];
  const int tid = threadIdx.x;
  const int k0 = blockIdx.x * 64;
  const int j0 = blockIdx.y * 64;
  const int sr = tid >> 3;
  const int sc = (tid & 7) << 3;
#pragma unroll
  for (int rr = sr; rr < 64; rr += 32) {
    const float* s = sym + (size_t)(j0 + rr) * 1024 + k0 + sc;
    float4 f0 = *(const float4*)s;
    float4 f1 = *(const float4*)(s + 4);
    t[rr][sc + 0] = (short)f2b(f0.x); t[rr][sc + 1] = (short)f2b(f0.y);
    t[rr][sc + 2] = (short)f2b(f0.z); t[rr][sc + 3] = (short)f2b(f0.w);
    t[rr][sc + 4] = (short)f2b(f1.x); t[rr][sc + 5] = (short)f2b(f1.y);
    t[rr][sc + 6] = (short)f2b(f1.z); t[rr][sc + 7] = (short)f2b(f1.w);
  }
  __syncthreads();
  const int kk = tid >> 4;
  const int jj = (tid & 15) << 2;
#pragma unroll
  for (int k = kk; k < 64; k += 16) {
    short* dst = symT + (size_t)(k0 + k) * 512 + j0 + jj;
    dst[0] = t[jj + 0][k];
    dst[1] = t[jj + 1][k];
    dst[2] = t[jj + 2][k];
    dst[3] = t[jj + 3][k];
  }
}

// ---------------------------------------------------------------------------
// Kernel 3: score. logitsT = MT @ bf16(inp)^T (swapped operands), row max,
// P = bf16(exp(x - m)) UNNORMALIZED -> global ws, rowinv = 1/rowsum (fp32).
// grid 512 (64-row tiles), block 512 (8 waves), wave owns a 64-j strip.
// R5 structure (barrier per 64-col tile, ping-pong buffers, rule-18 fences),
// K-loop unrolled x2 with PREFETCH DISTANCE 2 for the inp HBM loads (two
// named float4 register pairs) so ~600+ cyc of load slack covers HBM latency.
// __launch_bounds__(512,2) — NOT 4: R6 showed (512,4) causes scratch spills.
// ---------------------------------------------------------------------------
__global__ __launch_bounds__(512, 2) void score_kernel(
    const float* __restrict__ inp, const short* __restrict__ MT,
    short* __restrict__ P, float* __restrict__ rowinv) {
  __shared__ short Abuf[2][64 * 64];
  __shared__ float redmax[8 * 64];
  __shared__ float redsum[8 * 64];

  const int tid = threadIdx.x;
  const int wid = tid >> 6;
  const int lane = tid & 63;
  const int ml = lane & 15;
  const int g = lane >> 4;
  const size_t row0 = (size_t)blockIdx.x * 64;

  float4_t acc[4][4];  // acc[jm][rm]: D[j][r], j = wid*64+jm*16+g*4+i, r = rm*16+ml
#pragma unroll
  for (int a = 0; a < 4; ++a)
#pragma unroll
    for (int b = 0; b < 4; ++b) acc[a][b] = (float4_t)(0.0f);

  const int sr = tid >> 3;        // 0..63 row within tile
  const int sc = (tid & 7) << 3;  // col chunk
  const float* srcbase = inp + (row0 + sr) * 1024 + sc;
  const short* mtbase = MT + (size_t)(wid * 64 + ml) * 1024 + g * 8;
  const int lds_off = ((sr * 64 + sc) * 2) ^ ((sr & 7) << 4);

  // prefetch tiles 0 (set A) and 1 (set B)
  float4 a0 = *(const float4*)(srcbase);
  float4 a1 = *(const float4*)(srcbase + 4);
  float4 b0 = *(const float4*)(srcbase + 64);
  float4 b1 = *(const float4*)(srcbase + 68);

  for (int s = 0; s < 8; ++s) {
    // ================= even tile kt = 2s (set A -> buf 0) =================
    *(short8_t*)((char*)Abuf[0] + lds_off) = pack8(a0, a1);
    const short* mtb0 = mtbase + (size_t)(2 * s) * 64;
    short8_t af0[4], af1[4];
#pragma unroll
    for (int jm = 0; jm < 4; ++jm) {
      af0[jm] = *(const short8_t*)(mtb0 + jm * 16 * 1024);
      af1[jm] = *(const short8_t*)(mtb0 + jm * 16 * 1024 + 32);
    }
    if (s < 7) {  // prefetch tile 2s+2 into set A (distance 2)
      const float* s2 = srcbase + (2 * s + 2) * 64;
      a0 = *(const float4*)s2;
      a1 = *(const float4*)(s2 + 4);
    }
    // drain own LDS write; global loads stay in flight
    asm volatile("s_waitcnt lgkmcnt(0)" ::: "memory");
    __builtin_amdgcn_s_barrier();
    __builtin_amdgcn_sched_barrier(0);
    {
      const char* bb = (const char*)Abuf[0];
#pragma unroll
      for (int ks = 0; ks < 2; ++ks) {
        const int col = ks * 32 + g * 8;
        short8_t bfr[4];
#pragma unroll
        for (int rm = 0; rm < 4; ++rm) {
          int row = rm * 16 + ml;
          bfr[rm] = *(const short8_t*)(bb + (((row * 64 + col) * 2) ^ ((row & 7) << 4)));
        }
#pragma unroll
        for (int jm = 0; jm < 4; ++jm)
#pragma unroll
          for (int rm = 0; rm < 4; ++rm)
            acc[jm][rm] = MFMA16(ks == 0 ? af0[jm] : af1[jm], bfr[rm], acc[jm][rm]);
      }
    }
    // ================= odd tile kt = 2s+1 (set B -> buf 1) =================
    *(short8_t*)((char*)Abuf[1] + lds_off) = pack8(b0, b1);
    const short* mtb1 = mtbase + (size_t)(2 * s + 1) * 64;
    short8_t ag0[4], ag1[4];
#pragma unroll
    for (int jm = 0; jm < 4; ++jm) {
      ag0[jm] = *(const short8_t*)(mtb1 + jm * 16 * 1024);
      ag1[jm] = *(const short8_t*)(mtb1 + jm * 16 * 1024 + 32);
    }
    if (s < 7) {  // prefetch tile 2s+3 into set B (distance 2)
      const float* s2 = srcbase + (2 * s + 3) * 64;
      b0 = *(const float4*)s2;
      b1 = *(const float4*)(s2 + 4);
    }
    asm volatile("s_waitcnt lgkmcnt(0)" ::: "memory");
    __builtin_amdgcn_s_barrier();
    __builtin_amdgcn_sched_barrier(0);
    {
      const char* bb = (const char*)Abuf[1];
#pragma unroll
      for (int ks = 0; ks < 2; ++ks) {
        const int col = ks * 32 + g * 8;
        short8_t bfr[4];
#pragma unroll
        for (int rm = 0; rm < 4; ++rm) {
          int row = rm * 16 + ml;
          bfr[rm] = *(const short8_t*)(bb + (((row * 64 + col) * 2) ^ ((row & 7) << 4)));
        }
#pragma unroll
        for (int jm = 0; jm < 4; ++jm)
#pragma unroll
          for (int rm = 0; rm < 4; ++rm)
            acc[jm][rm] = MFMA16(ks == 0 ? ag0[jm] : ag1[jm], bfr[rm], acc[jm][rm]);
      }
    }
  }

  // ---- row max over j (512), rows r = rm*16+ml ----
#pragma unroll
  for (int rm = 0; rm < 4; ++rm) {
    float mx = -1e30f;
#pragma unroll
    for (int jm = 0; jm < 4; ++jm)
#pragma unroll
      for (int i = 0; i < 4; ++i) mx = fmaxf(mx, acc[jm][rm][i]);
    mx = fmaxf(mx, __shfl_xor(mx, 16));
    mx = fmaxf(mx, __shfl_xor(mx, 32));
    if (g == 0) redmax[wid * 64 + rm * 16 + ml] = mx;
  }
  __syncthreads();

  // ---- exp(x-m), write unnormalized bf16 P, reduce row sums ----
#pragma unroll
  for (int rm = 0; rm < 4; ++rm) {
    const int row = rm * 16 + ml;
    float m = redmax[row];
#pragma unroll
    for (int w = 1; w < 8; ++w) m = fmaxf(m, redmax[w * 64 + row]);
    float s = 0.0f;
#pragma unroll
    for (int jm = 0; jm < 4; ++jm) {
      short4_t pv;
#pragma unroll
      for (int i = 0; i < 4; ++i) {
        float p = __expf(acc[jm][rm][i] - m);
        s += p;
        pv[i] = (short)f2b(p);
      }
      *(short4_t*)(P + ((row0 + row) << 9) + wid * 64 + jm * 16 + g * 4) = pv;
    }
    s += __shfl_xor(s, 16);
    s += __shfl_xor(s, 32);
    if (g == 0) redsum[wid * 64 + row] = s;
  }
  __syncthreads();

  // ---- wave 0 writes 1/rowsum ----
  if (wid == 0 && g == 0) {
#pragma unroll
    for (int rm = 0; rm < 4; ++rm) {
      const int row = rm * 16 + ml;
      float t = 0.0f;
#pragma unroll
      for (int w = 0; w < 8; ++w) t += redsum[w * 64 + row];
      rowinv[row0 + row] = 1.0f / t;
    }
  }
}

// ---------------------------------------------------------------------------
// Kernel 4: out[r][d] = rowinv[r] * sum_j P[r][j] * symT[d][j].  128x128 tile,
// 256 threads (4 waves, 2x2). A (P) staged via gload_lds double-buffer with
// the R5-proven inverse-permuted-source swizzle; B (symT, 1MB, L2-hot in
// every XCD) read DIRECTLY from global as b128 fragments, prefetched one
// tile ahead into named register sets (score's proven pre-barrier pattern).
// Stage loads halve (8->4/iter), LDS halves (32KB) -> higher occupancy.
// XCD-bijective block swizzle (2048 % 8 == 0).
// ---------------------------------------------------------------------------
__global__ __launch_bounds__(256, 2) void pv_kernel(
    const short* __restrict__ P, const short* __restrict__ symT,
    const float* __restrict__ rowinv, float* __restrict__ out) {
  __shared__ short Abuf[2][128 * 64];
  const int tid = threadIdx.x;
  const int lane = tid & 63;
  const int ml = lane & 15;
  const int g = lane >> 4;
  const int wid = tid >> 6;
  const int wr = wid >> 1;
  const int wc = wid & 1;

  const int b = blockIdx.x;
  const int swz = (b & 7) * 256 + (b >> 3);
  const size_t m0 = (size_t)(swz >> 3) * 128;
  const int n0 = (swz & 7) * 128;

  float4_t acc[4][4];
#pragma unroll
  for (int a = 0; a < 4; ++a)
#pragma unroll
    for (int c = 0; c < 4; ++c) acc[a][c] = (float4_t)(0.0f);

  // B fragment base: row = n0 + wc*64 + nr*16 + ml, col chunk g*8
  const short* bbase = symT + (size_t)(n0 + wc * 64 + ml) * 512 + g * 8;

  // A staging with source col-chunk permutation: chunk ^ (row & 7)
#define STAGE_A(t, buf)                                                      \
  {                                                                          \
    const int kc_ = (t) * 64;                                                \
    _Pragma("unroll")                                                        \
    for (int i_ = 0; i_ < 4; ++i_) {                                         \
      const int c_ = tid + i_ * 256;                                         \
      const int r_ = c_ >> 3;                                                \
      const int ck_ = ((c_ & 7) ^ (r_ & 7)) << 3;                            \
      GLOAD_LDS16(P + (m0 + r_) * 512 + kc_ + ck_,                           \
                  (char*)Abuf[buf] + c_ * 16);                               \
    }                                                                        \
  }

#define LOAD_BF(d0v, d1v, t)                                                 \
  _Pragma("unroll")                                                          \
  for (int nr_ = 0; nr_ < 4; ++nr_) {                                        \
    d0v[nr_] = *(const short8_t*)(bbase + (size_t)nr_ * 16 * 512 + (t) * 64);      \
    d1v[nr_] = *(const short8_t*)(bbase + (size_t)nr_ * 16 * 512 + (t) * 64 + 32); \
  }

#define COMPUTE(bufidx, bf0v, bf1v)                                          \
  {                                                                          \
    const char* ab_ = (const char*)Abuf[bufidx];                             \
    _Pragma("unroll")                                                        \
    for (int ks = 0; ks < 2; ++ks) {                                         \
      const int col = ks * 32 + g * 8;                                       \
      short8_t af[4];                                                        \
      _Pragma("unroll")                                                      \
      for (int mr = 0; mr < 4; ++mr) {                                       \
        const int row = wr * 64 + mr * 16 + ml;                              \
        af[mr] = *(const short8_t*)(ab_ +                                    \
                  (((row * 64 + col) * 2) ^ ((row & 7) << 4)));              \
      }                                                                      \
      _Pragma("unroll")                                                      \
      for (int mr = 0; mr < 4; ++mr)                                         \
        _Pragma("unroll")                                                    \
        for (int nr = 0; nr < 4; ++nr)                                       \
          acc[mr][nr] =                                                      \
              MFMA16(af[mr], (ks == 0 ? bf0v[nr] : bf1v[nr]), acc[mr][nr]);  \
    }                                                                        \
  }

  short8_t bfA0[4], bfA1[4], bfB0[4], bfB1[4];

  STAGE_A(0, 0);
  LOAD_BF(bfA0, bfA1, 0);
  asm volatile("s_waitcnt vmcnt(0)" ::: "memory");
  __builtin_amdgcn_s_barrier();
  __builtin_amdgcn_sched_barrier(0);

  for (int s = 0; s < 4; ++s) {
    // ---- even tile t=2s (Abuf[0], bfA) ----
    STAGE_A(2 * s + 1, 1);
    LOAD_BF(bfB0, bfB1, 2 * s + 1);
    COMPUTE(0, bfA0, bfA1);
    asm volatile("s_waitcnt vmcnt(0)" ::: "memory");
    __builtin_amdgcn_s_barrier();
    __builtin_amdgcn_sched_barrier(0);
    // ---- odd tile t=2s+1 (Abuf[1], bfB) ----
    if (s < 3) {
      STAGE_A(2 * s + 2, 0);
      LOAD_BF(bfA0, bfA1, 2 * s + 2);
    }
    COMPUTE(1, bfB0, bfB1);
    asm volatile("s_waitcnt vmcnt(0)" ::: "memory");
    __builtin_amdgcn_s_barrier();
    __builtin_amdgcn_sched_barrier(0);
  }
#undef STAGE_A
#undef LOAD_BF
#undef COMPUTE

#pragma unroll
  for (int mr = 0; mr < 4; ++mr)
#pragma unroll
    for (int i = 0; i < 4; ++i) {
      const size_t r = m0 + wr * 64 + mr * 16 + g * 4 + i;
      const float inv = rowinv[r];
#pragma unroll
      for (int nr = 0; nr < 4; ++nr)
        out[r * 1024 + n0 + wc * 64 + nr * 16 + ml] = acc[mr][nr][i] * inv;
    }
}

extern "C" void kernel_launch(void* const* d_in, const int* in_sizes, int n_in,
                              void* d_out, int out_size, void* d_ws,
                              size_t ws_size, hipStream_t stream) {
  const float* inp = (const float*)d_in[0];      // [8,4096,1024]
  const float* Wq = (const float*)d_in[1];       // [1024,1024]
  const float* binding = (const float*)d_in[2];  // [512,1024]
  const float* symbols = (const float*)d_in[3];  // [512,1024]
  float* out = (float*)d_out;                    // [8,4096,1024]

  short* MT = (short*)d_ws;            // [512][1024] bf16 (1/32 scale folded)
  short* symT = MT + 512 * 1024;       // [1024][512] bf16
  short* P = symT + 1024 * 512;        // [32768][512] bf16 unnormalized exp
  float* rowinv = (float*)(P + (size_t)32768 * 512);  // [32768] fp32

  mt_kernel<<<dim3(8, 8), 256, 0, stream>>>(Wq, binding, MT);
  tr_kernel<<<dim3(16, 8), 256, 0, stream>>>(symbols, symT);
  score_kernel<<<512, 512, 0, stream>>>(inp, MT, P, rowinv);
  pv_kernel<<<2048, 256, 0, stream>>>(P, symT, rowinv, out);
}